// Round 4
// baseline (378.178 us; speedup 1.0000x reference)
//
#include <hip/hip_runtime.h>
#include <stdint.h>

typedef __bf16 bf16;
typedef __bf16 bf16x4 __attribute__((ext_vector_type(4)));
typedef __bf16 bf16x8 __attribute__((ext_vector_type(8)));
typedef float f32x4 __attribute__((ext_vector_type(4)));

#define CN 524288    // C*N = 512*1024 (per-batch x elements)
#define NPIX 1024
#define CCH 512

// ---- async global->LDS, 16B per lane ----
__device__ __forceinline__ void gload_lds16(const void* g, void* l) {
  auto gp = reinterpret_cast<const __attribute__((address_space(1))) uint32_t*>(
      reinterpret_cast<uintptr_t>(g));
  auto lp = reinterpret_cast<__attribute__((address_space(3))) uint32_t*>(
      static_cast<uint32_t>(reinterpret_cast<uintptr_t>(l)));
  __builtin_amdgcn_global_load_lds(gp, lp, 16, 0, 0);
}

// ======================================================================
// gemm_bt: C[i,j] = sum_k A[i,k] * Bt[j,k]
// 256x256 tile, BK=32, 8 waves (512 thr, 2Mx4N -> 128x64 per wave),
// TRIPLE-buffered LDS (96 KB): compute tile kt (buf0) while tile kt+1
// (buf1) is fully resident and tile kt+2 streams into buf2 -> no
// intra-tile barriers needed; one s_barrier + counted vmcnt(4)/tile.
// Ledger (4 gloads/thread/tile, grouped per tile):
//   prologue: T0(4), T1(4)
//   iter kt checkpoint: vmcnt(4) -> newest 4 = T(kt+1)'s; all of T(kt)
//   landed. Then 2 phases: {stage 2 of T(kt+2); ds_read 8/4; lgkmcnt(0);
//   sched_barrier; setprio(1); 16 MFMA; setprio(0)}.
// XOR swizzle for 64B rows: stored seg = gseg ^ (row&3), applied on the
// pre-swizzled GLOBAL source and on the ds_read address (involution).
// EPI 0: QKV   (bias; j<1024 -> qkT[i][j], else v[j-1024][i])
// EPI 1: scores (fp32 out, * scale)
// EPI 2: PV    (bf16 out, ld=512)
// EPI 3: proj  (fp32 out + proj_b[i] + resid)
// ======================================================================
template<int EPI>
__global__ __launch_bounds__(512, 2)
void gemm_bt(const bf16* __restrict__ A, int lda, long long sA,
             const bf16* __restrict__ Bt, int ldb, long long sB,
             char* __restrict__ Cp, long long sC,
             char* __restrict__ C2p, long long sC2,
             const float* __restrict__ bias,
             const float* __restrict__ resid,
             int K, float scale)
{
  __shared__ __align__(16) bf16 As3[3][8192];   // 3 x [256][32]
  __shared__ __align__(16) bf16 Bs3[3][8192];
  const int t = threadIdx.x;
  const int w = t >> 6;
  const int l = t & 63;
  const int z = blockIdx.z;
  A  += (long long)z * sA;
  Bt += (long long)z * sB;
  Cp += (long long)z * sC;
  if (C2p) C2p += (long long)z * sC2;
  const float* residb = (EPI == 3) ? (resid + (long long)z * CN) : nullptr;

  const int row0 = blockIdx.x * 256;
  const int col0 = blockIdx.y * 256;
  const int wr = w >> 2;              // 0..1 : wave row group (128 rows)
  const int wc = w & 3;               // 0..3 : wave col group (64 cols)

  f32x4 acc[8][4] = {};

  // ---- staging geometry: chunk = 128 rows x 32 cols bf16 = 8KB ----
  const int srow = t >> 2;                       // 0..127 row within chunk
  const int gseg = ((t & 3) ^ (srow & 3)) << 3;  // pre-swizzled k-seg (elems)
  const bf16* gA = A  + (long long)(row0 + srow) * lda + gseg;
  const bf16* gB = Bt + (long long)(col0 + srow) * ldb + gseg;
  const int ldsd = w * 512;                      // + chunk*4096, elem offset/8 = t

  auto stA = [&](int kt, int buf, int c) {
    gload_lds16(gA + (long long)(c * 128) * lda + kt * 32,
                &As3[buf][c * 4096 + ldsd]);
  };
  auto stB = [&](int kt, int buf, int c) {
    gload_lds16(gB + (long long)(c * 128) * ldb + kt * 32,
                &Bs3[buf][c * 4096 + ldsd]);
  };

  // ---- fragment-read geometry ----
  const int lrow = l & 15;
  const int sega = (((l >> 4) ^ (lrow & 3))) << 3;   // swizzled seg offset

  const int nt = K >> 5;

  // prologue: T0 -> buf0, T1 -> buf1 (4 loads each, grouped)
  stB(0, 0, 0); stB(0, 0, 1); stA(0, 0, 0); stA(0, 0, 1);
  stB(1, 1, 0); stB(1, 1, 1); stA(1, 1, 0); stA(1, 1, 1);

  int bcur = 0, bnxt = 1, bstg = 2;

  #pragma unroll 1
  for (int kt = 0; kt < nt; ++kt) {
    if (kt + 1 < nt) {
      asm volatile("s_waitcnt vmcnt(4)" ::: "memory");
    } else {
      asm volatile("s_waitcnt vmcnt(0)" ::: "memory");
    }
    __builtin_amdgcn_sched_barrier(0);
    __builtin_amdgcn_s_barrier();
    asm volatile("" ::: "memory");

    const bf16* Ab = As3[bcur];
    const bf16* Bb = Bs3[bcur];
    const bool st = (kt + 2) < nt;

    // ---- phase 0: stage B(kt+2); read bF[4] + aF_lo[4]; MFMA mh=0 ----
    if (st) { stB(kt + 2, bstg, 0); stB(kt + 2, bstg, 1); }
    bf16x8 bF[4], aF[4];
    #pragma unroll
    for (int nf = 0; nf < 4; ++nf)
      bF[nf] = *(const bf16x8*)&Bb[(wc * 64 + nf * 16 + lrow) * 32 + sega];
    #pragma unroll
    for (int mf = 0; mf < 4; ++mf)
      aF[mf] = *(const bf16x8*)&Ab[(wr * 128 + mf * 16 + lrow) * 32 + sega];
    asm volatile("s_waitcnt lgkmcnt(0)" ::: "memory");
    __builtin_amdgcn_sched_barrier(0);
    __builtin_amdgcn_s_setprio(1);
    #pragma unroll
    for (int mf = 0; mf < 4; ++mf)
      #pragma unroll
      for (int nf = 0; nf < 4; ++nf)
        acc[mf][nf] = __builtin_amdgcn_mfma_f32_16x16x32_bf16(aF[mf], bF[nf], acc[mf][nf], 0, 0, 0);
    __builtin_amdgcn_s_setprio(0);

    // ---- phase 1: stage A(kt+2); read aF_hi[4]; MFMA mh=1 ----
    if (st) { stA(kt + 2, bstg, 0); stA(kt + 2, bstg, 1); }
    #pragma unroll
    for (int mf = 0; mf < 4; ++mf)
      aF[mf] = *(const bf16x8*)&Ab[(wr * 128 + 64 + mf * 16 + lrow) * 32 + sega];
    asm volatile("s_waitcnt lgkmcnt(0)" ::: "memory");
    __builtin_amdgcn_sched_barrier(0);
    __builtin_amdgcn_s_setprio(1);
    #pragma unroll
    for (int mf = 0; mf < 4; ++mf)
      #pragma unroll
      for (int nf = 0; nf < 4; ++nf)
        acc[4 + mf][nf] = __builtin_amdgcn_mfma_f32_16x16x32_bf16(aF[mf], bF[nf], acc[4 + mf][nf], 0, 0, 0);
    __builtin_amdgcn_s_setprio(0);

    const int tb = bcur; bcur = bnxt; bnxt = bstg; bstg = tb;
  }

  (void)scale;
  const int ci = (l >> 4) * 4;
  const int cj = l & 15;
  #pragma unroll
  for (int mf = 0; mf < 8; ++mf) {
    const int i0 = row0 + wr * 128 + mf * 16 + ci;
    #pragma unroll
    for (int nf = 0; nf < 4; ++nf) {
      const int j = col0 + wc * 64 + nf * 16 + cj;
      const f32x4 a = acc[mf][nf];
      if constexpr (EPI == 0) {
        const float bj = bias[j];
        if (j < NPIX) {
          bf16* q = (bf16*)Cp;
          #pragma unroll
          for (int r = 0; r < 4; ++r)
            q[(i0 + r) * NPIX + j] = (bf16)(a[r] + bj);
        } else {
          bf16* vb = (bf16*)C2p;
          #pragma unroll
          for (int r = 0; r < 4; ++r)
            vb[(j - NPIX) * NPIX + (i0 + r)] = (bf16)(a[r] + bj);
        }
      } else if constexpr (EPI == 1) {
        float* sp = (float*)Cp;
        #pragma unroll
        for (int r = 0; r < 4; ++r)
          sp[(i0 + r) * NPIX + j] = a[r] * scale;
      } else if constexpr (EPI == 2) {
        bf16* hp = (bf16*)Cp;
        #pragma unroll
        for (int r = 0; r < 4; ++r)
          hp[(i0 + r) * CCH + j] = (bf16)a[r];
      } else {
        float* op = (float*)Cp;
        #pragma unroll
        for (int r = 0; r < 4; ++r)
          op[(i0 + r) * NPIX + j] = a[r] + bias[i0 + r] + residb[(i0 + r) * NPIX + j];
      }
    }
  }
}

// ---- fused GroupNorm: one block per (batch,group); 16ch x 1024px in LDS,
//      stats + normalize + transpose-write hnT[n][c] (bf16) in one pass ----
__global__ __launch_bounds__(256)
void gn_fused(const float* __restrict__ x, const float* __restrict__ gw,
              const float* __restrict__ gb, bf16* __restrict__ hnT)
{
  __shared__ float xs[16 * 1024];   // 64 KB
  __shared__ float red[8];
  const int b = blockIdx.x >> 5;
  const int g = blockIdx.x & 31;
  const float* xp = x + ((long long)b * CCH + g * 16) * NPIX;
  const int t = threadIdx.x;

  float4* xsv = (float4*)xs;
  const float4* gv = (const float4*)xp;
  float s = 0.f, ss = 0.f;
  #pragma unroll
  for (int i = 0; i < 16; ++i) {
    float4 v = gv[t + i * 256];
    xsv[t + i * 256] = v;
    s  += v.x + v.y + v.z + v.w;
    ss += v.x * v.x + v.y * v.y + v.z * v.z + v.w * v.w;
  }
  #pragma unroll
  for (int o = 32; o; o >>= 1) { s += __shfl_xor(s, o); ss += __shfl_xor(ss, o); }
  if ((t & 63) == 0) { red[t >> 6] = s; red[4 + (t >> 6)] = ss; }
  __syncthreads();
  s  = red[0] + red[1] + red[2] + red[3];
  ss = red[4] + red[5] + red[6] + red[7];
  const float mean = s * (1.f / 16384.f);
  const float var  = ss * (1.f / 16384.f) - mean * mean;
  const float rstd = rsqrtf(var + 1e-5f);

  float ac[16], bc[16];
  #pragma unroll
  for (int c = 0; c < 16; ++c) {
    const float wv = gw[g * 16 + c] * rstd;
    ac[c] = wv;
    bc[c] = gb[g * 16 + c] - mean * wv;
  }

  bf16* hp = hnT + (long long)b * CN + g * 16;
  #pragma unroll
  for (int r = 0; r < 4; ++r) {
    const int n = t + r * 256;
    bf16x8 o0, o1;
    #pragma unroll
    for (int c = 0; c < 8; ++c)
      o0[c] = (bf16)(xs[c * 1024 + n] * ac[c] + bc[c]);
    #pragma unroll
    for (int c = 0; c < 8; ++c)
      o1[c] = (bf16)(xs[(8 + c) * 1024 + n] * ac[8 + c] + bc[8 + c]);
    *(bf16x8*)&hp[(long long)n * CCH]     = o0;
    *(bf16x8*)&hp[(long long)n * CCH + 8] = o1;
  }
}

// ---- row softmax over 1024 fp32, write bf16 IN PLACE (row stride 4KB) ----
__global__ __launch_bounds__(256)
void softmax_rows(float* __restrict__ scores)
{
  float* p = scores + (long long)blockIdx.x * NPIX;
  const int t = threadIdx.x;
  const float4 v = ((const float4*)p)[t];
  float m = fmaxf(fmaxf(v.x, v.y), fmaxf(v.z, v.w));
  #pragma unroll
  for (int o = 32; o; o >>= 1) m = fmaxf(m, __shfl_xor(m, o));
  __shared__ float red[4];
  if ((t & 63) == 0) red[t >> 6] = m;
  __syncthreads();
  m = fmaxf(fmaxf(red[0], red[1]), fmaxf(red[2], red[3]));
  float4 e;
  e.x = __expf(v.x - m); e.y = __expf(v.y - m);
  e.z = __expf(v.z - m); e.w = __expf(v.w - m);
  float s = e.x + e.y + e.z + e.w;
  #pragma unroll
  for (int o = 32; o; o >>= 1) s += __shfl_xor(s, o);
  __syncthreads();
  if ((t & 63) == 0) red[t >> 6] = s;
  __syncthreads();
  s = red[0] + red[1] + red[2] + red[3];
  const float inv = 1.f / s;
  bf16x4 ov;
  ov[0] = (bf16)(e.x * inv); ov[1] = (bf16)(e.y * inv);
  ov[2] = (bf16)(e.z * inv); ov[3] = (bf16)(e.w * inv);
  *(bf16x4*)((bf16*)p + t * 4) = ov;
}

// ---- fp32 -> bf16 weight conversion (once) ----
__global__ __launch_bounds__(256)
void cvt_weights(const float* __restrict__ qw, const float* __restrict__ pw,
                 bf16* __restrict__ qwb, bf16* __restrict__ pwb)
{
  const int i = blockIdx.x * 256 + threadIdx.x;
  if (i < 3 * CCH * CCH) qwb[i] = (bf16)qw[i];
  if (i < CCH * CCH) pwb[i] = (bf16)pw[i];
}

extern "C" void kernel_launch(void* const* d_in, const int* in_sizes, int n_in,
                              void* d_out, int out_size, void* d_ws, size_t ws_size,
                              hipStream_t stream)
{
  const float* x      = (const float*)d_in[0];
  const float* gn_w   = (const float*)d_in[1];
  const float* gn_b   = (const float*)d_in[2];
  const float* qkv_w  = (const float*)d_in[3];
  const float* qkv_b  = (const float*)d_in[4];
  const float* proj_w = (const float*)d_in[5];
  const float* proj_b = (const float*)d_in[6];
  float* out = (float*)d_out;
  (void)in_sizes; (void)n_in; (void)out_size;

  char* ws = (char*)d_ws;
  size_t off = 0;
  auto alloc = [&](size_t bytes) -> char* {
    char* p = ws + off;
    off += (bytes + 255) & ~(size_t)255;
    return p;
  };
  bf16* qkv_wb  = (bf16*)alloc(3 * 512 * 512 * 2);
  bf16* proj_wb = (bf16*)alloc(512 * 512 * 2);
  const size_t fixed = off;
  // per-batch: hnT 1MB + qkT 2MB + v 1MB + scores 4MB + hvT 1MB
  const size_t per = 1048576ull + 2097152ull + 1048576ull + 4194304ull + 1048576ull;
  int Bc = 32;
  if (ws_size > fixed) {
    size_t fit = (ws_size - fixed) / per;
    if (fit < 32) Bc = (int)fit;
  } else {
    Bc = 0;
  }
  if (Bc < 1) Bc = 1;

  bf16*  hnT    = (bf16*) alloc((size_t)Bc * 1048576);
  bf16*  qkT    = (bf16*) alloc((size_t)Bc * 2097152);
  bf16*  vbuf   = (bf16*) alloc((size_t)Bc * 1048576);
  float* scores = (float*)alloc((size_t)Bc * 4194304);
  bf16*  hvT    = (bf16*) alloc((size_t)Bc * 1048576);

  cvt_weights<<<dim3(3072), 256, 0, stream>>>(qkv_w, proj_w, qkv_wb, proj_wb);

  const float scale = 0.044194173824159216f;  // 512^-0.5
  for (int b0 = 0; b0 < 32; b0 += Bc) {
    const int bc = (32 - b0 < Bc) ? (32 - b0) : Bc;
    const float* xb = x + (size_t)b0 * CN;

    gn_fused<<<dim3(bc * 32), 256, 0, stream>>>(xb, gn_w, gn_b, hnT);

    // QKV: [n][o] = hnT[n][c] . qkv_w[o][c];  q,k -> qkT[n][0..1023], v -> vbuf[c][m]
    gemm_bt<0><<<dim3(4, 6, bc), 512, 0, stream>>>(
        hnT, 512, 524288, qkv_wb, 512, 0,
        (char*)qkT, 2097152, (char*)vbuf, 1048576, qkv_b, nullptr, 512, 1.f);

    // scores[n][m] = q[n][:] . k[m][:]  (fp32, *scale)
    gemm_bt<1><<<dim3(4, 4, bc), 512, 0, stream>>>(
        qkT, 1024, 1048576, qkT + 512, 1024, 1048576,
        (char*)scores, 4194304, nullptr, 0, nullptr, nullptr, 512, scale);

    softmax_rows<<<dim3(bc * 1024), 256, 0, stream>>>(scores);

    // hvT[n][c] = attn[n][m] . v[c][m]   (attn bf16 in-place, lda=2048 elems)
    gemm_bt<2><<<dim3(4, 2, bc), 512, 0, stream>>>(
        (const bf16*)scores, 2048, 2097152, vbuf, 1024, 524288,
        (char*)hvT, 1048576, nullptr, 0, nullptr, nullptr, 1024, 1.f);

    // out[c][n] = proj_w[c][:] . hvT[n][:] + proj_b[c] + x[c][n]
    gemm_bt<3><<<dim3(2, 4, bc), 512, 0, stream>>>(
        proj_wb, 512, 0, hvT, 512, 524288,
        (char*)(out + (size_t)b0 * CN), 2097152, nullptr, 0, proj_b, xb, 512, 1.f);
  }
}

// Round 5
// 372.983 us; speedup vs baseline: 1.0139x; 1.0139x over previous
//
#include <hip/hip_runtime.h>
#include <stdint.h>

typedef __bf16 bf16;
typedef __bf16 bf16x4 __attribute__((ext_vector_type(4)));
typedef __bf16 bf16x8 __attribute__((ext_vector_type(8)));
typedef float f32x4 __attribute__((ext_vector_type(4)));

#define CN 524288    // C*N = 512*1024 (per-batch x elements)
#define NPIX 1024
#define CCH 512

// ---- async global->LDS, 16B per lane ----
__device__ __forceinline__ void gload_lds16(const void* g, void* l) {
  auto gp = reinterpret_cast<const __attribute__((address_space(1))) uint32_t*>(
      reinterpret_cast<uintptr_t>(g));
  auto lp = reinterpret_cast<__attribute__((address_space(3))) uint32_t*>(
      static_cast<uint32_t>(reinterpret_cast<uintptr_t>(l)));
  __builtin_amdgcn_global_load_lds(gp, lp, 16, 0, 0);
}

// ======================================================================
// gemm_bt: C[i,j] = sum_k A[i,k] * Bt[j,k]
// 256x256 tile, BK=64, 8 waves (512 thr). Wave (wr=w>>2, wc=w&3) owns a
// 128x64 output sub-tile. LDS = dbuf x half: As[2][2][128*64] + Bs same
// (128 KB). GROUP-LOCAL staging: each half-tile (128 rows x 64 k, one
// operand) is staged by the SAME 4-wave group that reads it (wave stages
// 32 rows of its own A-half wr and of its own B-half wc>>1) -> per-wave
// vmcnt exactly covers its group's data.
// Schedule per K-tile (4 phases):
//  ph0: issue ALL 8 gloads for kt+1 (A c0..3, B c0..3) -> buf^1;
//       ds_read bF(kk0) x4 + aF_lo(kk0) x4; lgkm0; prio1; 16 MFMA; barrier
//  ph1: ds_read aF_hi(kk0) x4; 16 MFMA; barrier
//  ph2: ds_read bF(kk1) x4 + aF_lo(kk1) x4; 16 MFMA; barrier
//  ph3: ds_read aF_hi(kk1) x4; 16 MFMA; vmcnt(0) [~3 phases of cover];
//       barrier  -> buffer switch safe
// XOR swizzle (r2-verified, 0 conflicts): stored seg s = g ^ (row&7);
// applied on pre-swizzled GLOBAL source and on ds_read address.
// EPI 0: QKV (bias; j<1024 -> qkT[i][j], else v[j-1024][i])
// EPI 1: scores (fp32, * scale)   EPI 2: PV (bf16, ld=512)
// EPI 3: proj (fp32 + proj_b[i] + resid)
// ======================================================================
template<int EPI>
__global__ __launch_bounds__(512)
void gemm_bt(const bf16* __restrict__ A, int lda, long long sA,
             const bf16* __restrict__ Bt, int ldb, long long sB,
             char* __restrict__ Cp, long long sC,
             char* __restrict__ C2p, long long sC2,
             const float* __restrict__ bias,
             const float* __restrict__ resid,
             int K, float scale)
{
  __shared__ __align__(16) bf16 As[2][2][8192];   // [dbuf][half][128*64]
  __shared__ __align__(16) bf16 Bs[2][2][8192];
  const int t = threadIdx.x;
  const int w = t >> 6;
  const int l = t & 63;
  const int z = blockIdx.z;
  A  += (long long)z * sA;
  Bt += (long long)z * sB;
  Cp += (long long)z * sC;
  if (C2p) C2p += (long long)z * sC2;
  const float* residb = (EPI == 3) ? (resid + (long long)z * CN) : nullptr;

  const int row0 = blockIdx.x * 256;
  const int col0 = blockIdx.y * 256;
  const int wr = w >> 2;              // A-half this wave reads & stages
  const int wc = w & 3;
  const int bh = wc >> 1;             // B-half this wave reads & stages
  const int bq = wr * 2 + (wc & 1);   // 0..3 sub-partition within B-half group

  f32x4 acc[8][4] = {};

  // ---- staging geometry: per gload, 64 lanes cover 8 rows x 8 segs ----
  const int sr8 = l >> 3;                       // row within 8-row block
  const int sseg = ((l & 7) ^ sr8) << 3;        // pre-swizzled k-seg (elems)
  const bf16* gAw = A  + (long long)(row0 + wr * 128 + wc * 32 + sr8) * lda + sseg;
  const bf16* gBw = Bt + (long long)(col0 + bh * 128 + bq * 32 + sr8) * ldb + sseg;

  auto stA = [&](int kt, int buf, int c) {
    gload_lds16(gAw + (long long)(c * 8) * lda + kt * 64,
                &As[buf][wr][(wc * 32 + c * 8) * 64]);
  };
  auto stB = [&](int kt, int buf, int c) {
    gload_lds16(gBw + (long long)(c * 8) * ldb + kt * 64,
                &Bs[buf][bh][(bq * 32 + c * 8) * 64]);
  };

  // ---- fragment-read geometry (r2-verified swizzle) ----
  const int lrow = l & 15;
  const int lx = l & 7;                    // == row&7 for all fragment rows
  const int s0 = (((l >> 4)) ^ lx) << 3;       // kk=0 seg offset
  const int s1 = (((l >> 4) + 4) ^ lx) << 3;   // kk=1
  const int rbb = (wc & 1) * 64 + lrow;        // B row base within half

  const int nt = K >> 6;

  // prologue: tile 0 -> buf 0
  #pragma unroll
  for (int c = 0; c < 4; ++c) stA(0, 0, c);
  #pragma unroll
  for (int c = 0; c < 4; ++c) stB(0, 0, c);
  asm volatile("s_waitcnt vmcnt(0)" ::: "memory");
  __builtin_amdgcn_s_barrier();
  asm volatile("" ::: "memory");

  #pragma unroll 1
  for (int kt = 0; kt < nt; ++kt) {
    const int cur = kt & 1, nxt = cur ^ 1;
    const bool pf = (kt + 1) < nt;
    const bf16* Ab = As[cur][wr];
    const bf16* Bb = Bs[cur][bh];
    bf16x8 bF[4], aF[4];

    // ---- ph0: issue all 8 prefetch gloads; bF kk0 + aF_lo kk0; MFMA ----
    if (pf) {
      #pragma unroll
      for (int c = 0; c < 4; ++c) stA(kt + 1, nxt, c);
      #pragma unroll
      for (int c = 0; c < 4; ++c) stB(kt + 1, nxt, c);
    }
    #pragma unroll
    for (int nf = 0; nf < 4; ++nf)
      bF[nf] = *(const bf16x8*)&Bb[(rbb + nf * 16) * 64 + s0];
    #pragma unroll
    for (int mf = 0; mf < 4; ++mf)
      aF[mf] = *(const bf16x8*)&Ab[(mf * 16 + lrow) * 64 + s0];
    asm volatile("s_waitcnt lgkmcnt(0)" ::: "memory");
    __builtin_amdgcn_sched_barrier(0);
    __builtin_amdgcn_s_setprio(1);
    #pragma unroll
    for (int mf = 0; mf < 4; ++mf)
      #pragma unroll
      for (int nf = 0; nf < 4; ++nf)
        acc[mf][nf] = __builtin_amdgcn_mfma_f32_16x16x32_bf16(aF[mf], bF[nf], acc[mf][nf], 0, 0, 0);
    __builtin_amdgcn_s_setprio(0);
    asm volatile("" ::: "memory");
    __builtin_amdgcn_s_barrier();

    // ---- ph1: aF_hi kk0; MFMA ----
    #pragma unroll
    for (int mf = 0; mf < 4; ++mf)
      aF[mf] = *(const bf16x8*)&Ab[(64 + mf * 16 + lrow) * 64 + s0];
    asm volatile("s_waitcnt lgkmcnt(0)" ::: "memory");
    __builtin_amdgcn_sched_barrier(0);
    __builtin_amdgcn_s_setprio(1);
    #pragma unroll
    for (int mf = 0; mf < 4; ++mf)
      #pragma unroll
      for (int nf = 0; nf < 4; ++nf)
        acc[4 + mf][nf] = __builtin_amdgcn_mfma_f32_16x16x32_bf16(aF[mf], bF[nf], acc[4 + mf][nf], 0, 0, 0);
    __builtin_amdgcn_s_setprio(0);
    asm volatile("" ::: "memory");
    __builtin_amdgcn_s_barrier();

    // ---- ph2: bF kk1 + aF_lo kk1; MFMA ----
    #pragma unroll
    for (int nf = 0; nf < 4; ++nf)
      bF[nf] = *(const bf16x8*)&Bb[(rbb + nf * 16) * 64 + s1];
    #pragma unroll
    for (int mf = 0; mf < 4; ++mf)
      aF[mf] = *(const bf16x8*)&Ab[(mf * 16 + lrow) * 64 + s1];
    asm volatile("s_waitcnt lgkmcnt(0)" ::: "memory");
    __builtin_amdgcn_sched_barrier(0);
    __builtin_amdgcn_s_setprio(1);
    #pragma unroll
    for (int mf = 0; mf < 4; ++mf)
      #pragma unroll
      for (int nf = 0; nf < 4; ++nf)
        acc[mf][nf] = __builtin_amdgcn_mfma_f32_16x16x32_bf16(aF[mf], bF[nf], acc[mf][nf], 0, 0, 0);
    __builtin_amdgcn_s_setprio(0);
    asm volatile("" ::: "memory");
    __builtin_amdgcn_s_barrier();

    // ---- ph3: aF_hi kk1; MFMA; drain prefetch; buffer-switch barrier ----
    #pragma unroll
    for (int mf = 0; mf < 4; ++mf)
      aF[mf] = *(const bf16x8*)&Ab[(64 + mf * 16 + lrow) * 64 + s1];
    asm volatile("s_waitcnt lgkmcnt(0)" ::: "memory");
    __builtin_amdgcn_sched_barrier(0);
    __builtin_amdgcn_s_setprio(1);
    #pragma unroll
    for (int mf = 0; mf < 4; ++mf)
      #pragma unroll
      for (int nf = 0; nf < 4; ++nf)
        acc[4 + mf][nf] = __builtin_amdgcn_mfma_f32_16x16x32_bf16(aF[mf], bF[nf], acc[4 + mf][nf], 0, 0, 0);
    __builtin_amdgcn_s_setprio(0);
    asm volatile("s_waitcnt vmcnt(0)" ::: "memory");
    __builtin_amdgcn_sched_barrier(0);
    __builtin_amdgcn_s_barrier();
    asm volatile("" ::: "memory");
  }

  (void)scale;
  const int ci = (l >> 4) * 4;
  const int cj = l & 15;
  #pragma unroll
  for (int mf = 0; mf < 8; ++mf) {
    const int i0 = row0 + wr * 128 + mf * 16 + ci;
    #pragma unroll
    for (int nf = 0; nf < 4; ++nf) {
      const int j = col0 + wc * 64 + nf * 16 + cj;
      const f32x4 a = acc[mf][nf];
      if constexpr (EPI == 0) {
        const float bj = bias[j];
        if (j < NPIX) {
          bf16* q = (bf16*)Cp;
          #pragma unroll
          for (int r = 0; r < 4; ++r)
            q[(i0 + r) * NPIX + j] = (bf16)(a[r] + bj);
        } else {
          bf16* vb = (bf16*)C2p;
          #pragma unroll
          for (int r = 0; r < 4; ++r)
            vb[(j - NPIX) * NPIX + (i0 + r)] = (bf16)(a[r] + bj);
        }
      } else if constexpr (EPI == 1) {
        float* sp = (float*)Cp;
        #pragma unroll
        for (int r = 0; r < 4; ++r)
          sp[(i0 + r) * NPIX + j] = a[r] * scale;
      } else if constexpr (EPI == 2) {
        bf16* hp = (bf16*)Cp;
        #pragma unroll
        for (int r = 0; r < 4; ++r)
          hp[(i0 + r) * CCH + j] = (bf16)a[r];
      } else {
        float* op = (float*)Cp;
        #pragma unroll
        for (int r = 0; r < 4; ++r)
          op[(i0 + r) * NPIX + j] = a[r] + bias[i0 + r] + residb[(i0 + r) * NPIX + j];
      }
    }
  }
}

// ---- fused GroupNorm: one block per (batch,group); 16ch x 1024px in LDS,
//      stats + normalize + transpose-write hnT[n][c] (bf16) in one pass ----
__global__ __launch_bounds__(256)
void gn_fused(const float* __restrict__ x, const float* __restrict__ gw,
              const float* __restrict__ gb, bf16* __restrict__ hnT)
{
  __shared__ float xs[16 * 1024];   // 64 KB
  __shared__ float red[8];
  const int b = blockIdx.x >> 5;
  const int g = blockIdx.x & 31;
  const float* xp = x + ((long long)b * CCH + g * 16) * NPIX;
  const int t = threadIdx.x;

  float4* xsv = (float4*)xs;
  const float4* gv = (const float4*)xp;
  float s = 0.f, ss = 0.f;
  #pragma unroll
  for (int i = 0; i < 16; ++i) {
    float4 v = gv[t + i * 256];
    xsv[t + i * 256] = v;
    s  += v.x + v.y + v.z + v.w;
    ss += v.x * v.x + v.y * v.y + v.z * v.z + v.w * v.w;
  }
  #pragma unroll
  for (int o = 32; o; o >>= 1) { s += __shfl_xor(s, o); ss += __shfl_xor(ss, o); }
  if ((t & 63) == 0) { red[t >> 6] = s; red[4 + (t >> 6)] = ss; }
  __syncthreads();
  s  = red[0] + red[1] + red[2] + red[3];
  ss = red[4] + red[5] + red[6] + red[7];
  const float mean = s * (1.f / 16384.f);
  const float var  = ss * (1.f / 16384.f) - mean * mean;
  const float rstd = rsqrtf(var + 1e-5f);

  float ac[16], bc[16];
  #pragma unroll
  for (int c = 0; c < 16; ++c) {
    const float wv = gw[g * 16 + c] * rstd;
    ac[c] = wv;
    bc[c] = gb[g * 16 + c] - mean * wv;
  }

  bf16* hp = hnT + (long long)b * CN + g * 16;
  #pragma unroll
  for (int r = 0; r < 4; ++r) {
    const int n = t + r * 256;
    bf16x8 o0, o1;
    #pragma unroll
    for (int c = 0; c < 8; ++c)
      o0[c] = (bf16)(xs[c * 1024 + n] * ac[c] + bc[c]);
    #pragma unroll
    for (int c = 0; c < 8; ++c)
      o1[c] = (bf16)(xs[(8 + c) * 1024 + n] * ac[8 + c] + bc[8 + c]);
    *(bf16x8*)&hp[(long long)n * CCH]     = o0;
    *(bf16x8*)&hp[(long long)n * CCH + 8] = o1;
  }
}

// ---- row softmax over 1024 fp32, write bf16 IN PLACE (row stride 4KB) ----
__global__ __launch_bounds__(256)
void softmax_rows(float* __restrict__ scores)
{
  float* p = scores + (long long)blockIdx.x * NPIX;
  const int t = threadIdx.x;
  const float4 v = ((const float4*)p)[t];
  float m = fmaxf(fmaxf(v.x, v.y), fmaxf(v.z, v.w));
  #pragma unroll
  for (int o = 32; o; o >>= 1) m = fmaxf(m, __shfl_xor(m, o));
  __shared__ float red[4];
  if ((t & 63) == 0) red[t >> 6] = m;
  __syncthreads();
  m = fmaxf(fmaxf(red[0], red[1]), fmaxf(red[2], red[3]));
  float4 e;
  e.x = __expf(v.x - m); e.y = __expf(v.y - m);
  e.z = __expf(v.z - m); e.w = __expf(v.w - m);
  float s = e.x + e.y + e.z + e.w;
  #pragma unroll
  for (int o = 32; o; o >>= 1) s += __shfl_xor(s, o);
  __syncthreads();
  if ((t & 63) == 0) red[t >> 6] = s;
  __syncthreads();
  s = red[0] + red[1] + red[2] + red[3];
  const float inv = 1.f / s;
  bf16x4 ov;
  ov[0] = (bf16)(e.x * inv); ov[1] = (bf16)(e.y * inv);
  ov[2] = (bf16)(e.z * inv); ov[3] = (bf16)(e.w * inv);
  *(bf16x4*)((bf16*)p + t * 4) = ov;
}

// ---- fp32 -> bf16 weight conversion (once) ----
__global__ __launch_bounds__(256)
void cvt_weights(const float* __restrict__ qw, const float* __restrict__ pw,
                 bf16* __restrict__ qwb, bf16* __restrict__ pwb)
{
  const int i = blockIdx.x * 256 + threadIdx.x;
  if (i < 3 * CCH * CCH) qwb[i] = (bf16)qw[i];
  if (i < CCH * CCH) pwb[i] = (bf16)pw[i];
}

extern "C" void kernel_launch(void* const* d_in, const int* in_sizes, int n_in,
                              void* d_out, int out_size, void* d_ws, size_t ws_size,
                              hipStream_t stream)
{
  const float* x      = (const float*)d_in[0];
  const float* gn_w   = (const float*)d_in[1];
  const float* gn_b   = (const float*)d_in[2];
  const float* qkv_w  = (const float*)d_in[3];
  const float* qkv_b  = (const float*)d_in[4];
  const float* proj_w = (const float*)d_in[5];
  const float* proj_b = (const float*)d_in[6];
  float* out = (float*)d_out;
  (void)in_sizes; (void)n_in; (void)out_size;

  char* ws = (char*)d_ws;
  size_t off = 0;
  auto alloc = [&](size_t bytes) -> char* {
    char* p = ws + off;
    off += (bytes + 255) & ~(size_t)255;
    return p;
  };
  bf16* qkv_wb  = (bf16*)alloc(3 * 512 * 512 * 2);
  bf16* proj_wb = (bf16*)alloc(512 * 512 * 2);
  const size_t fixed = off;
  // per-batch: hnT 1MB + qkT 2MB + v 1MB + scores 4MB + hvT 1MB
  const size_t per = 1048576ull + 2097152ull + 1048576ull + 4194304ull + 1048576ull;
  int Bc = 32;
  if (ws_size > fixed) {
    size_t fit = (ws_size - fixed) / per;
    if (fit < 32) Bc = (int)fit;
  } else {
    Bc = 0;
  }
  if (Bc < 1) Bc = 1;

  bf16*  hnT    = (bf16*) alloc((size_t)Bc * 1048576);
  bf16*  qkT    = (bf16*) alloc((size_t)Bc * 2097152);
  bf16*  vbuf   = (bf16*) alloc((size_t)Bc * 1048576);
  float* scores = (float*)alloc((size_t)Bc * 4194304);
  bf16*  hvT    = (bf16*) alloc((size_t)Bc * 1048576);

  cvt_weights<<<dim3(3072), 256, 0, stream>>>(qkv_w, proj_w, qkv_wb, proj_wb);

  const float scale = 0.044194173824159216f;  // 512^-0.5
  for (int b0 = 0; b0 < 32; b0 += Bc) {
    const int bc = (32 - b0 < Bc) ? (32 - b0) : Bc;
    const float* xb = x + (size_t)b0 * CN;

    gn_fused<<<dim3(bc * 32), 256, 0, stream>>>(xb, gn_w, gn_b, hnT);

    // QKV: [n][o] = hnT[n][c] . qkv_w[o][c];  q,k -> qkT[n][0..1023], v -> vbuf[c][m]
    gemm_bt<0><<<dim3(4, 6, bc), 512, 0, stream>>>(
        hnT, 512, 524288, qkv_wb, 512, 0,
        (char*)qkT, 2097152, (char*)vbuf, 1048576, qkv_b, nullptr, 512, 1.f);

    // scores[n][m] = q[n][:] . k[m][:]  (fp32, *scale)
    gemm_bt<1><<<dim3(4, 4, bc), 512, 0, stream>>>(
        qkT, 1024, 1048576, qkT + 512, 1024, 1048576,
        (char*)scores, 4194304, nullptr, 0, nullptr, nullptr, 512, scale);

    softmax_rows<<<dim3(bc * 1024), 256, 0, stream>>>(scores);

    // hvT[n][c] = attn[n][m] . v[c][m]   (attn bf16 in-place, lda=2048 elems)
    gemm_bt<2><<<dim3(4, 2, bc), 512, 0, stream>>>(
        (const bf16*)scores, 2048, 2097152, vbuf, 1024, 524288,
        (char*)hvT, 1048576, nullptr, 0, nullptr, nullptr, 1024, 1.f);

    // out[c][n] = proj_w[c][:] . hvT[n][:] + proj_b[c] + x[c][n]
    gemm_bt<3><<<dim3(2, 4, bc), 512, 0, stream>>>(
        proj_wb, 512, 0, hvT, 512, 524288,
        (char*)(out + (size_t)b0 * CN), 2097152, nullptr, 0, proj_b, xb, 512, 1.f);
  }
}